// Round 12
// baseline (212.397 us; speedup 1.0000x reference)
//
#include <hip/hip_runtime.h>
#include <hip/hip_bf16.h>

#define NODES_DIM 64   // H*D = 4*16
#define SL_DIM    12   // H*DC = 4*3
#define CAP       64   // bucket capacity; deg ~ Poisson(16), P(>=64) ~ 1e-18
#define CSTRIDE   16   // cursor padded to one counter per 64B line

// round-to-nearest-even fp32 -> bf16
__device__ __forceinline__ unsigned short f2bf(float f) {
    union { float f; unsigned u; } x; x.f = f;
    const unsigned r = x.u + 0x7FFFu + ((x.u >> 16) & 1u);
    return (unsigned short)(r >> 16);
}

// ---------------------------------------------------------------------------
// Fused kernel: heterogeneous grid, role = blockIdx&1, NO LDS AT ALL.
//  qkv role (even): 2 groups of 32 rows via grid-stride. W read straight
//    from global per k4 (coalesced dword loads; 48 KB stays L1/L2-hot; all
//    4 waves of a block read identical W addresses -> L1 reuse). h loads
//    wave-uniform -> scalar. Q fp32; K,V packed bf16 (KV = v<<16 | k).
//    Dropping the 48 KB LDS lifts occupancy for BOTH roles (23% -> VGPR-
//    limited), which is what the latency-bound fill role needs.
//  fill role (odd): 1024 edges/block, 4 stride-256 edges/thread, atomics
//    batched before the dependent stores. cursor strided to 1 counter per
//    64B line: same-line atomic serialization 256 -> 16 RMWs/line.
// ---------------------------------------------------------------------------
__global__ __launch_bounds__(256) void qkv_fill_kernel(
    const float* __restrict__ h,
    const float* __restrict__ Wq, const float* __restrict__ bq,
    const float* __restrict__ Wk, const float* __restrict__ bk,
    const float* __restrict__ Wv, const float* __restrict__ bv,
    float* __restrict__ Q, unsigned* __restrict__ KV, int N,
    const int* __restrict__ src, const int* __restrict__ dst,
    int* __restrict__ cursor, int* __restrict__ list, int E,
    int ngroupsQ, int half)
{
    const int role = blockIdx.x & 1;
    const int g    = blockIdx.x >> 1;

    if (role == 1) {
        // ---------------- fill role ----------------
        const int e0 = g * 1024 + (int)threadIdx.x;
        int sv[4], dv[4];
        bool ok[4];
#pragma unroll
        for (int j = 0; j < 4; ++j) {
            const int e = e0 + j * 256;
            ok[j] = e < E;
            sv[j] = ok[j] ? __builtin_nontemporal_load(src + e) : 0;
            dv[j] = ok[j] ? __builtin_nontemporal_load(dst + e) : 0;
        }
        int pos[4];
#pragma unroll
        for (int j = 0; j < 4; ++j)
            pos[j] = ok[j] ? atomicAdd(&cursor[dv[j] * CSTRIDE], 1) : CAP;
#pragma unroll
        for (int j = 0; j < 4; ++j) {
            if (ok[j] && pos[j] < CAP)
                __builtin_nontemporal_store(
                    sv[j], &list[((size_t)dv[j] << 6) + pos[j]]);
        }
        return;
    }

    // ---------------- qkv role ----------------
    const int c    = threadIdx.x & 63;
    const int slot = __builtin_amdgcn_readfirstlane((int)(threadIdx.x >> 6));
    const float bqc = bq[c], bkc = bk[c], bvc = bv[c];

    for (int gq = g; gq < ngroupsQ; gq += half) {
        const int rowBase = gq * 32 + slot * 8;
        if (rowBase >= N) continue;
        const int nrows = (N - rowBase < 8) ? (N - rowBase) : 8;

        float acc0[8], acc1[8], acc2[8];
#pragma unroll
        for (int rr = 0; rr < 8; ++rr) { acc0[rr] = 0.f; acc1[rr] = 0.f; acc2[rr] = 0.f; }

        if (nrows == 8) {
#pragma unroll 4
            for (int k4 = 0; k4 < 16; ++k4) {
                float4 hv[8];
#pragma unroll
                for (int rr = 0; rr < 8; ++rr)
                    hv[rr] = ((const float4*)(h + (size_t)(rowBase + rr) * 64))[k4];
                float wqv[4], wkv[4], wvv[4];
#pragma unroll
                for (int kk = 0; kk < 4; ++kk) {
                    const int k = k4 * 4 + kk;
                    wqv[kk] = Wq[k * 64 + c];
                    wkv[kk] = Wk[k * 64 + c];
                    wvv[kk] = Wv[k * 64 + c];
                }
#pragma unroll
                for (int kk = 0; kk < 4; ++kk) {
#pragma unroll
                    for (int rr = 0; rr < 8; ++rr) {
                        const float hh = (&hv[rr].x)[kk];
                        acc0[rr] += hh * wqv[kk];
                        acc1[rr] += hh * wkv[kk];
                        acc2[rr] += hh * wvv[kk];
                    }
                }
            }
        } else {
            for (int k4 = 0; k4 < 16; ++k4) {
                float4 hv[8];
#pragma unroll
                for (int rr = 0; rr < 8; ++rr)
                    hv[rr] = (rr < nrows)
                        ? ((const float4*)(h + (size_t)(rowBase + rr) * 64))[k4]
                        : make_float4(0.f, 0.f, 0.f, 0.f);
                float wqv[4], wkv[4], wvv[4];
#pragma unroll
                for (int kk = 0; kk < 4; ++kk) {
                    const int k = k4 * 4 + kk;
                    wqv[kk] = Wq[k * 64 + c];
                    wkv[kk] = Wk[k * 64 + c];
                    wvv[kk] = Wv[k * 64 + c];
                }
#pragma unroll
                for (int kk = 0; kk < 4; ++kk) {
#pragma unroll
                    for (int rr = 0; rr < 8; ++rr) {
                        const float hh = (&hv[rr].x)[kk];
                        acc0[rr] += hh * wqv[kk];
                        acc1[rr] += hh * wkv[kk];
                        acc2[rr] += hh * wvv[kk];
                    }
                }
            }
        }

#pragma unroll
        for (int rr = 0; rr < 8; ++rr) {
            if (rr < nrows) {
                const size_t o = (size_t)(rowBase + rr) * 64 + c;
                Q[o] = acc0[rr] + bqc;
                const unsigned short kb = f2bf(acc1[rr] + bkc);
                const unsigned short vb = f2bf(acc2[rr] + bvc);
                KV[o] = ((unsigned)vb << 16) | (unsigned)kb;
            }
        }
    }
}

// ---------------------------------------------------------------------------
// Node phase, edge-quad layout (R6-proven, unchanged except cursor stride).
// One wave per node. lane = e2*16 + head*4 + quad. Per 4-edge group:
// 1 dwordx4 KV load/lane, width-4 2-stage shfl reduce, exp amortized,
// V accumulated in-lane.
// ---------------------------------------------------------------------------
__global__ __launch_bounds__(256) void node_kernel(
    const float* __restrict__ Q, const unsigned* __restrict__ KV,
    const float* __restrict__ s_l,
    const int* __restrict__ cursor, const int* __restrict__ list,
    float* __restrict__ out, int N)
{
    const int t = blockIdx.x * 256 + threadIdx.x;
    const int node = t >> 6;
    if (node >= N) return;
    const int lane = threadIdx.x & 63;
    const int e2   = lane >> 4;
    const int hq   = lane & 15;
    const int head = hq >> 2;
    const int quad = hq & 3;

    int deg = cursor[node * CSTRIDE];
    deg = (deg > CAP) ? CAP : deg;

    const float4 qv = *(const float4*)(Q + (size_t)node * 64 + (hq << 2));
    const float slv = (quad < 3) ? s_l[(size_t)node * SL_DIM + head * 3 + quad] : 0.f;

    const int* lbase = list + ((size_t)node << 6);

    float4 accV = make_float4(0.f, 0.f, 0.f, 0.f);
    float zs = 0.f;

    const int ng = (deg + 3) >> 2;
#pragma unroll 2
    for (int i = 0; i < ng; ++i) {
        const int slot  = (i << 2) + e2;
        const bool valid = slot < deg;
        const int sidx  = lbase[valid ? slot : 0];

        const uint4 kv = *(const uint4*)(KV + (size_t)sidx * 64 + (hq << 2));
        const float a  = (quad < 3) ? s_l[(size_t)sidx * SL_DIM + head * 3 + quad] : 0.f;

        float dt = __uint_as_float(kv.x << 16) * qv.x
                 + __uint_as_float(kv.y << 16) * qv.y
                 + __uint_as_float(kv.z << 16) * qv.z
                 + __uint_as_float(kv.w << 16) * qv.w;
        const float df = a - slv;
        float ds = df * df;

        dt += __shfl_xor(dt, 1, 4);
        dt += __shfl_xor(dt, 2, 4);
        ds += __shfl_xor(ds, 1, 4);
        ds += __shfl_xor(ds, 2, 4);

        const float sc = fminf(fmaxf(dt * 0.25f, -5.f), 5.f);
        float score = __expf(sc);
        score = valid ? score : 0.f;
        const float w    = __expf(-ds * ds);
        const float news = score * w;
        zs += score;

        accV.x += __uint_as_float(kv.x & 0xFFFF0000u) * news;
        accV.y += __uint_as_float(kv.y & 0xFFFF0000u) * news;
        accV.z += __uint_as_float(kv.z & 0xFFFF0000u) * news;
        accV.w += __uint_as_float(kv.w & 0xFFFF0000u) * news;
    }

#pragma unroll
    for (int m = 16; m <= 32; m <<= 1) {
        accV.x += __shfl_xor(accV.x, m);
        accV.y += __shfl_xor(accV.y, m);
        accV.z += __shfl_xor(accV.z, m);
        accV.w += __shfl_xor(accV.w, m);
        zs     += __shfl_xor(zs, m);
    }

    if (e2 == 0) {
        const float inv = (zs > 0.f) ? (1.f / zs) : 1.f;
        float4 o;
        o.x = accV.x * inv; o.y = accV.y * inv;
        o.z = accV.z * inv; o.w = accV.w * inv;
        *(float4*)(out + (size_t)node * 64 + (hq << 2)) = o;
    }
}

extern "C" void kernel_launch(void* const* d_in, const int* in_sizes, int n_in,
                              void* d_out, int out_size, void* d_ws, size_t ws_size,
                              hipStream_t stream) {
    const float* h   = (const float*)d_in[0];
    const float* s_l = (const float*)d_in[1];
    const float* Wq  = (const float*)d_in[2];
    const float* bq  = (const float*)d_in[3];
    const float* Wk  = (const float*)d_in[4];
    const float* bk  = (const float*)d_in[5];
    const float* Wv  = (const float*)d_in[6];
    const float* bv  = (const float*)d_in[7];
    const int*   src = (const int*)d_in[8];
    const int*   dst = (const int*)d_in[9];
    float* out = (float*)d_out;

    const int N = in_sizes[0] / 64;   // 50000
    const int E = in_sizes[8];        // 800000

    // workspace: Q fp32 (N*64) | KV packed (N*64) | cursor (N*CSTRIDE int,
    // one counter per 64B line) | list int (N*64)   => ~41.6 MB
    float*    Q      = (float*)d_ws;
    unsigned* KV     = (unsigned*)(Q + (size_t)N * NODES_DIM);
    int*      cursor = (int*)(KV + (size_t)N * NODES_DIM);
    int*      list   = cursor + (size_t)N * CSTRIDE;

    hipMemsetAsync(cursor, 0, (size_t)N * CSTRIDE * sizeof(int), stream);

    // heterogeneous grid: parity roles, fill=782 blocks (1024 edges each),
    // qkv=782 blocks grid-striding 1563 groups of 32 rows (2 groups/block)
    const int ngroupsQ = (N + 31) / 32;        // 1563
    const int fbc      = (E + 1023) / 1024;    // 782
    const int half     = fbc;
    qkv_fill_kernel<<<2 * fbc, 256, 0, stream>>>(
        h, Wq, bq, Wk, bk, Wv, bv, Q, KV, N,
        src, dst, cursor, list, E, ngroupsQ, half);

    const long long nthreads = (long long)N * 64;
    node_kernel<<<(int)((nthreads + 255) / 256), 256, 0, stream>>>(
        Q, KV, s_l, cursor, list, out, N);
}